// Round 6
// baseline (769.293 us; speedup 1.0000x reference)
//
#include <hip/hip_runtime.h>

#define E_N 200000
#define T_N 500000
#define NB_SCAN 196   // ceil(E_N/1024)

typedef __attribute__((ext_vector_type(8))) short bf16x8;
typedef __attribute__((ext_vector_type(4))) float f32x4;
typedef unsigned short u16;
typedef unsigned int u32;

// XOR swizzle for [row][128] bf16 LDS tiles (256B rows).
#define SWZ(b) ((b) ^ ((((b) >> 8) & 7) << 4))

// Explicit per-wave DMA drain before a barrier that publishes gl_lds data
// (round-3 post-timing race: compiler's implicit drain is not guaranteed).
#define SYNC_DRAIN() do { asm volatile("s_waitcnt vmcnt(0)" ::: "memory"); __syncthreads(); } while (0)

__device__ __forceinline__ u16 f2bf(float f){
  u32 u = __float_as_uint(f);
  return (u16)((u + 0x7fffu + ((u >> 16) & 1u)) >> 16);
}
__device__ __forceinline__ float bf2f(u16 v){
  return __uint_as_float(((u32)v) << 16);
}
__device__ __forceinline__ float silu_f(float v){
  return __fdividef(v, 1.f + __expf(-v));
}
__device__ __forceinline__ void gl_lds16(const void* g, void* l){
  __builtin_amdgcn_global_load_lds((const __attribute__((address_space(1))) u32*)g,
                                   (__attribute__((address_space(3))) u32*)l, 16, 0, 0);
}
__device__ __forceinline__ bf16x8 scale8(uint4 g, float s){
  union { bf16x8 v; u32 u[4]; } aa;
  u32 gu[4] = { g.x, g.y, g.z, g.w };
  #pragma unroll
  for (int q = 0; q < 4; q++){
    float lo = __uint_as_float(gu[q] << 16) * s;
    float hi = __uint_as_float(gu[q] & 0xffff0000u) * s;
    asm("v_cvt_pk_bf16_f32 %0, %1, %2" : "=v"(aa.u[q]) : "v"(lo), "v"(hi));
  }
  return aa.v;
}

// One wave computes 16 rows x 128 cols: A rows wv*16.., B = BT[n][k] swizzled.
__device__ __forceinline__ void gemm_tile(const char* ldsA, const char* ldsB,
                                          int wv, int lane, f32x4 acc[8]){
  const int arow = wv*16 + (lane & 15);
  const int kof = (lane >> 4) << 3;
  #pragma unroll
  for (int kc = 0; kc < 4; kc++){
    const int kb = (kc*32 + kof)*2;
    bf16x8 a = *(const bf16x8*)(ldsA + SWZ(arow*256 + kb));
    #pragma unroll
    for (int n = 0; n < 8; n++){
      bf16x8 b = *(const bf16x8*)(ldsB + SWZ((n*16 + (lane & 15))*256 + kb));
      acc[n] = __builtin_amdgcn_mfma_f32_16x16x32_bf16(a, b, acc[n], 0, 0, 0);
    }
  }
}

// ======================= CSR build =======================
__global__ __launch_bounds__(256) void k_zero32(u32* __restrict__ p, int n){
  int stride = gridDim.x * 256;
  for (int i = blockIdx.x*256 + threadIdx.x; i < n; i += stride) p[i] = 0u;
}
__global__ __launch_bounds__(256) void k_hist(const int* __restrict__ idx, u32* __restrict__ counts){
  int i = blockIdx.x*256 + threadIdx.x;
  if (i < T_N) atomicAdd(&counts[idx[i]], 1u);
}
// per-block sums of counts (1024 elems/block)
__global__ __launch_bounds__(1024) void k_scanA(const u32* __restrict__ counts, u32* __restrict__ bsum){
  __shared__ u32 red[16];
  int b = blockIdx.x, t = threadIdx.x, i = b*1024 + t;
  u32 v = (i < E_N) ? counts[i] : 0u;
  #pragma unroll
  for (int off = 1; off < 64; off <<= 1) v += __shfl_xor(v, off);
  if ((t & 63) == 0) red[t >> 6] = v;
  __syncthreads();
  if (t == 0){
    u32 s = 0;
    #pragma unroll
    for (int k = 0; k < 16; k++) s += red[k];
    bsum[b] = s;
  }
}
// exclusive scan of NB_SCAN block sums (single block)
__global__ __launch_bounds__(256) void k_scanB(const u32* __restrict__ bsum, u32* __restrict__ boff){
  __shared__ u32 wsum[4];
  int t = threadIdx.x, lane = t & 63, wv = t >> 6;
  u32 v = (t < NB_SCAN) ? bsum[t] : 0u;
  u32 x = v;
  #pragma unroll
  for (int off = 1; off < 64; off <<= 1){
    u32 y = __shfl_up(x, off);
    if (lane >= off) x += y;
  }
  if (lane == 63) wsum[wv] = x;
  __syncthreads();
  u32 wo = 0;
  for (int k = 0; k < wv; k++) wo += wsum[k];
  if (t < NB_SCAN) boff[t] = wo + x - v;
}
// full exclusive scan -> rowstart, cursor
__global__ __launch_bounds__(1024) void k_scanC(const u32* __restrict__ counts, const u32* __restrict__ boff,
                                                u32* __restrict__ rowstart, u32* __restrict__ cursor){
  __shared__ u32 wsum[16];
  int b = blockIdx.x, t = threadIdx.x, i = b*1024 + t;
  int lane = t & 63, wv = t >> 6;
  u32 v = (i < E_N) ? counts[i] : 0u;
  u32 x = v;
  #pragma unroll
  for (int off = 1; off < 64; off <<= 1){
    u32 y = __shfl_up(x, off);
    if (lane >= off) x += y;
  }
  if (lane == 63) wsum[wv] = x;
  __syncthreads();
  u32 wo = 0;
  for (int k = 0; k < wv; k++) wo += wsum[k];
  u32 ex = boff[b] + wo + x - v;
  if (i < E_N){ rowstart[i] = ex; cursor[i] = ex; }
  if (i == E_N - 1) rowstart[E_N] = ex + v;
}
__global__ __launch_bounds__(256) void k_fill(const int* __restrict__ idx, u32* __restrict__ cursor,
                                              u32* __restrict__ order){
  int i = blockIdx.x*256 + threadIdx.x;
  if (i < T_N){
    u32 p = atomicAdd(&cursor[idx[i]], 1u);
    order[p] = i;
  }
}

// ======================= prep =======================
__global__ __launch_bounds__(256) void k_cvt_W(const float* __restrict__ W, u16* __restrict__ out){
  int i = blockIdx.x*256 + threadIdx.x;   // 131072
  out[i] = f2bf(W[i]);
}
__global__ __launch_bounds__(256) void k_cvt_T(const float* __restrict__ jiw, const float* __restrict__ kjw,
                                               const float* __restrict__ bw, const float* __restrict__ lw,
                                               const float* __restrict__ aw, u16* __restrict__ out){
  int i = blockIdx.x*256 + threadIdx.x;   // 9*16384
  int m = i >> 14, o = i & 16383;
  int n = o >> 7, k = o & 127;
  const float* src;
  switch (m){
    case 0: src = jiw; break;
    case 1: src = kjw; break;
    case 2: src = bw; break;
    case 3: src = bw + 16384; break;
    case 4: src = lw; break;
    default: src = aw + (m - 5)*16384; break;
  }
  out[i] = f2bf(src[k*128 + n]);
}

// ======================= edge kernel =======================
__global__ __launch_bounds__(256) void k_edge(const float* __restrict__ x, const float* __restrict__ rbf,
    const float* __restrict__ rbfw, const u16* __restrict__ wji, const u16* __restrict__ wkj,
    const float* __restrict__ bji, const float* __restrict__ bkj,
    float* __restrict__ out, u16* __restrict__ xkj)
{
  __shared__ __align__(16) char ldsA[16384];
  __shared__ __align__(16) char ldsB[32768];
  __shared__ float lrbf[64*6];
  __shared__ float lrbfw[6*128];
  __shared__ float lbj[128];
  __shared__ float lbk[128];
  const int tid = threadIdx.x;
  const int e0 = blockIdx.x * 64;

  #pragma unroll
  for (int it = 0; it < 4; it++){
    int i = it*256 + tid;
    int row = i >> 4, c8 = (i & 15) << 3;
    const float4* s = (const float4*)(x + (e0 + row)*128 + c8);
    float4 v0 = s[0], v1 = s[1];
    union { u16 us[8]; uint4 q; } u;
    u.us[0]=f2bf(v0.x); u.us[1]=f2bf(v0.y); u.us[2]=f2bf(v0.z); u.us[3]=f2bf(v0.w);
    u.us[4]=f2bf(v1.x); u.us[5]=f2bf(v1.y); u.us[6]=f2bf(v1.z); u.us[7]=f2bf(v1.w);
    *(uint4*)(ldsA + SWZ(row*256 + c8*2)) = u.q;
  }
  #pragma unroll
  for (int it = 0; it < 8; it++){
    int p = (it*256 + tid)*16;
    int pb = __builtin_amdgcn_readfirstlane(p);
    int n = p >> 8, o = p & 255;
    gl_lds16((const char*)wji + n*256 + (o ^ ((n & 7) << 4)), ldsB + pb);
  }
  for (int i = tid; i < 384; i += 256) lrbf[i] = rbf[e0*6 + i];
  for (int i = tid; i < 768; i += 256) lrbfw[i] = rbfw[i];
  if (tid < 128){ lbj[tid] = bji[tid]; lbk[tid] = bkj[tid]; }
  SYNC_DRAIN();

  const int wv = tid >> 6, lane = tid & 63;
  const int colb = lane & 15, rgrp = (lane >> 4) << 2;
  f32x4 acc[8];
  #pragma unroll
  for (int n = 0; n < 8; n++)
    #pragma unroll
    for (int r = 0; r < 4; r++) acc[n][r] = 0.f;
  gemm_tile(ldsA, ldsB, wv, lane, acc);
  #pragma unroll
  for (int n = 0; n < 8; n++){
    int col = n*16 + colb;
    float b = lbj[col];
    #pragma unroll
    for (int r = 0; r < 4; r++){
      int row = e0 + wv*16 + rgrp + r;
      out[row*128 + col] = silu_f(acc[n][r] + b);
    }
  }
  __syncthreads();
  #pragma unroll
  for (int it = 0; it < 8; it++){
    int p = (it*256 + tid)*16;
    int pb = __builtin_amdgcn_readfirstlane(p);
    int n = p >> 8, o = p & 255;
    gl_lds16((const char*)wkj + n*256 + (o ^ ((n & 7) << 4)), ldsB + pb);
  }
  SYNC_DRAIN();
  #pragma unroll
  for (int n = 0; n < 8; n++)
    #pragma unroll
    for (int r = 0; r < 4; r++) acc[n][r] = 0.f;
  gemm_tile(ldsA, ldsB, wv, lane, acc);

  float rb[4][6];
  #pragma unroll
  for (int r = 0; r < 4; r++)
    #pragma unroll
    for (int c = 0; c < 6; c++) rb[r][c] = lrbf[(wv*16 + rgrp + r)*6 + c];
  #pragma unroll
  for (int n = 0; n < 8; n++){
    int col = n*16 + colb;
    float b = lbk[col];
    float wc[6];
    #pragma unroll
    for (int c = 0; c < 6; c++) wc[c] = lrbfw[c*128 + col];
    #pragma unroll
    for (int r = 0; r < 4; r++){
      float rp = 0.f;
      #pragma unroll
      for (int c = 0; c < 6; c++) rp += rb[r][c]*wc[c];
      int row = e0 + wv*16 + rgrp + r;
      xkj[row*128 + col] = f2bf(silu_f(acc[n][r] + b) * rp);
    }
  }
}

// ======================= triplet kernel =======================
__device__ __forceinline__ void stage_Wslice(const u16* __restrict__ Wbf, int j, char* dst, int tid){
  #pragma unroll
  for (int it = 0; it < 4; it++){
    int p = (it*512 + tid)*16;
    int pb = __builtin_amdgcn_readfirstlane(p);
    int n = p >> 8, o = p & 255;
    gl_lds16((const char*)Wbf + n*2048 + j*256 + (o ^ ((n & 7) << 4)), dst + pb);
  }
}

// CSR=1: plain coalesced bf16 stores of m-rows into mbuf[w] (no atomics).
// CSR=0: legacy f32 atomic scatter into out.
template<int CSR>
__global__ __launch_bounds__(512, 4) void k_trip(
    const u16* __restrict__ xkj, const float* __restrict__ sbf, const float* __restrict__ sbfw,
    const int* __restrict__ idx_kj, const int* __restrict__ idx_ji, const u16* __restrict__ Wbf,
    float* __restrict__ out, u16* __restrict__ mbuf)
{
  __shared__ __align__(16) char ldsW[2][32768];   // W dbuf; also sbf scratch pre-loop
  __shared__ float lss[256*8];
  __shared__ float lsw[336];
  __shared__ int lji[256];
  __shared__ int lkj[256];
  const int tid = threadIdx.x;
  const int t0 = blockIdx.x * 256;

  {
    float* scr = (float*)ldsW;
    for (int i = tid; i < 256*42; i += 512){
      int gi = t0*42 + i;
      scr[i] = (gi < T_N*42) ? sbf[gi] : 0.f;
    }
  }
  for (int i = tid; i < 336; i += 512) lsw[i] = sbfw[i];
  if (tid < 256){
    int w = t0 + tid;
    if (!CSR) lji[tid] = (w < T_N) ? idx_ji[w] : -1;
    lkj[tid] = (w < T_N) ? idx_kj[w] : 0;
  }
  __syncthreads();

  const int wv = tid >> 6, lane = tid & 63;
  const int r15 = lane & 15, q = lane >> 4;

  uint4 graw[8];   // [rt*4 + kc]
  #pragma unroll
  for (int rt = 0; rt < 2; rt++){
    int row = lkj[wv*32 + rt*16 + r15];
    const char* src = (const char*)xkj + (long)row*256 + q*16;
    #pragma unroll
    for (int kc = 0; kc < 4; kc++)
      graw[rt*4 + kc] = *(const uint4*)(src + kc*64);
  }
  if (tid < 256){
    const float* scr = (const float*)ldsW;
    float a[8];
    #pragma unroll
    for (int k = 0; k < 8; k++) a[k] = 0.f;
    for (int c = 0; c < 42; c++){
      float v = scr[tid*42 + c];
      #pragma unroll
      for (int k = 0; k < 8; k++) a[k] += v * lsw[c*8 + k];
    }
    #pragma unroll
    for (int k = 0; k < 8; k++) lss[tid*8 + k] = a[k];
  }
  __syncthreads();
  stage_Wslice(Wbf, 0, ldsW[0], tid);
  SYNC_DRAIN();

  f32x4 acc0[8], acc1[8];
  #pragma unroll
  for (int n = 0; n < 8; n++)
    #pragma unroll
    for (int r = 0; r < 4; r++){ acc0[n][r] = 0.f; acc1[n][r] = 0.f; }

  const int swz_lane = (r15 & 7) << 4;
  for (int j = 0; j < 8; j++){
    const char* bp = ldsW[j & 1];
    if (j < 7) stage_Wslice(Wbf, j + 1, ldsW[(j + 1) & 1], tid);
    const float s0 = lss[(wv*32 + r15)*8 + j];
    const float s1 = lss[(wv*32 + 16 + r15)*8 + j];
    #pragma unroll
    for (int kc = 0; kc < 4; kc++){
      const int ab = (r15*256 + q*16 + kc*64) ^ swz_lane;
      bf16x8 aa0 = scale8(graw[kc], s0);
      bf16x8 aa1 = scale8(graw[4 + kc], s1);
      #pragma unroll
      for (int n = 0; n < 8; n++){
        bf16x8 b = *(const bf16x8*)(bp + n*4096 + ab);
        acc0[n] = __builtin_amdgcn_mfma_f32_16x16x32_bf16(aa0, b, acc0[n], 0, 0, 0);
        acc1[n] = __builtin_amdgcn_mfma_f32_16x16x32_bf16(aa1, b, acc1[n], 0, 0, 0);
      }
    }
    if (j < 7) SYNC_DRAIN();
  }

  const int rgrp = q << 2;
  if (CSR){
    // pack col-pairs via shfl (validated in R5 PK path); coalesced u32 stores.
    const bool ev = (r15 & 1) == 0;
    #pragma unroll
    for (int n = 0; n < 8; n++){
      const int colb2 = (n*16 + (r15 & ~1))*2;
      #pragma unroll
      for (int r = 0; r < 4; r++){
        float v0 = acc0[n][r], p0 = __shfl_xor(v0, 1);
        float v1 = acc1[n][r], p1 = __shfl_xor(v1, 1);
        int row = wv*32 + (ev ? 0 : 16) + rgrp + r;
        u32 pk = ev ? ((u32)f2bf(v0) | ((u32)f2bf(p0) << 16))
                    : ((u32)f2bf(p1) | ((u32)f2bf(v1) << 16));
        if (t0 + row < T_N)
          *(u32*)((char*)mbuf + (size_t)(t0 + row)*256 + colb2) = pk;
      }
    }
  } else {
    #pragma unroll
    for (int n = 0; n < 8; n++){
      const int col = n*16 + r15;
      #pragma unroll
      for (int r = 0; r < 4; r++){
        int e0i = lji[wv*32 + rgrp + r];
        if (e0i >= 0) unsafeAtomicAdd(out + e0i*128 + col, acc0[n][r]);
        int e1i = lji[wv*32 + 16 + rgrp + r];
        if (e1i >= 0) unsafeAtomicAdd(out + e1i*128 + col, acc1[n][r]);
      }
    }
  }
}

// ======================= epilogue =======================
// CSR=1: h = x_ji + sum over CSR segment of mbuf rows; else hio already merged.
template<int CSR>
__global__ __launch_bounds__(256) void k_epi(
    const float* __restrict__ x, float* __restrict__ hio,
    const u32* __restrict__ rowstart, const u32* __restrict__ order, const u16* __restrict__ mbuf,
    const u16* __restrict__ wm,
    const float* __restrict__ bb2, const float* __restrict__ linb, const float* __restrict__ ab2)
{
  __shared__ __align__(16) char ldsA[16384];
  __shared__ __align__(16) char ldsB[32768];
  __shared__ float lbias[7][128];
  __shared__ u32 lrs[65];
  const int tid = threadIdx.x;
  const int e0 = blockIdx.x * 64;
  if (tid < 128){
    lbias[0][tid] = bb2[tid];
    lbias[1][tid] = bb2[128 + tid];
    lbias[2][tid] = linb[tid];
    lbias[3][tid] = ab2[tid];
    lbias[4][tid] = ab2[128 + tid];
    lbias[5][tid] = ab2[256 + tid];
    lbias[6][tid] = ab2[384 + tid];
  }
  if (CSR && tid < 65) lrs[tid] = rowstart[e0 + tid];
  const int wv = tid >> 6, lane = tid & 63;
  const int colb = lane & 15, rgrp = (lane >> 4) << 2;
  float h[8][4], t[8][4];
  f32x4 acc[8];
  #pragma unroll
  for (int n = 0; n < 8; n++)
    #pragma unroll
    for (int r = 0; r < 4; r++)
      h[n][r] = hio[(e0 + wv*16 + rgrp + r)*128 + n*16 + colb];

  if (CSR){
    __syncthreads();   // lrs ready (uniform branch)
    #pragma unroll
    for (int r = 0; r < 4; r++){
      u32 rs = lrs[wv*16 + rgrp + r], re = lrs[wv*16 + rgrp + r + 1];
      for (u32 d = rs; d < re; ++d){
        const u16* mrow = mbuf + (size_t)order[d]*128;
        #pragma unroll
        for (int n = 0; n < 8; n++)
          h[n][r] += bf2f(mrow[n*16 + colb]);
      }
    }
  }

#define STAGE_B(mi) { \
  _Pragma("unroll") \
  for (int it = 0; it < 8; it++){ \
    int p = (it*256 + tid)*16; \
    int pb = __builtin_amdgcn_readfirstlane(p); \
    int nn = p >> 8, o = p & 255; \
    gl_lds16((const char*)wm + (mi)*32768 + nn*256 + (o ^ ((nn & 7) << 4)), ldsB + pb); \
  } }
#define WRITE_A(v) { \
  _Pragma("unroll") \
  for (int n = 0; n < 8; n++){ \
    _Pragma("unroll") \
    for (int r = 0; r < 4; r++){ \
      int rowl = wv*16 + rgrp + r; \
      *(u16*)(ldsA + SWZ(rowl*256 + (n*16 + colb)*2)) = f2bf(v[n][r]); \
    } } }
#define RUN_GEMM() { \
  _Pragma("unroll") \
  for (int n = 0; n < 8; n++){ \
    _Pragma("unroll") \
    for (int r = 0; r < 4; r++) acc[n][r] = 0.f; } \
  gemm_tile(ldsA, ldsB, wv, lane, acc); }

  STAGE_B(0); WRITE_A(h); SYNC_DRAIN(); RUN_GEMM();
  #pragma unroll
  for (int n = 0; n < 8; n++){ float b = lbias[0][n*16 + colb];
    #pragma unroll
    for (int r = 0; r < 4; r++) t[n][r] = silu_f(acc[n][r] + b); }
  __syncthreads(); STAGE_B(1); WRITE_A(t); SYNC_DRAIN(); RUN_GEMM();
  #pragma unroll
  for (int n = 0; n < 8; n++){ float b = lbias[1][n*16 + colb];
    #pragma unroll
    for (int r = 0; r < 4; r++) h[n][r] += silu_f(acc[n][r] + b); }
  __syncthreads(); STAGE_B(2); WRITE_A(h); SYNC_DRAIN(); RUN_GEMM();
  #pragma unroll
  for (int n = 0; n < 8; n++){ float b = lbias[2][n*16 + colb];
    #pragma unroll
    for (int r = 0; r < 4; r++)
      h[n][r] = silu_f(acc[n][r] + b) + x[(e0 + wv*16 + rgrp + r)*128 + n*16 + colb]; }
  __syncthreads(); STAGE_B(3); WRITE_A(h); SYNC_DRAIN(); RUN_GEMM();
  #pragma unroll
  for (int n = 0; n < 8; n++){ float b = lbias[3][n*16 + colb];
    #pragma unroll
    for (int r = 0; r < 4; r++) t[n][r] = silu_f(acc[n][r] + b); }
  __syncthreads(); STAGE_B(4); WRITE_A(t); SYNC_DRAIN(); RUN_GEMM();
  #pragma unroll
  for (int n = 0; n < 8; n++){ float b = lbias[4][n*16 + colb];
    #pragma unroll
    for (int r = 0; r < 4; r++) h[n][r] += silu_f(acc[n][r] + b); }
  __syncthreads(); STAGE_B(5); WRITE_A(h); SYNC_DRAIN(); RUN_GEMM();
  #pragma unroll
  for (int n = 0; n < 8; n++){ float b = lbias[5][n*16 + colb];
    #pragma unroll
    for (int r = 0; r < 4; r++) t[n][r] = silu_f(acc[n][r] + b); }
  __syncthreads(); STAGE_B(6); WRITE_A(t); SYNC_DRAIN(); RUN_GEMM();
  #pragma unroll
  for (int n = 0; n < 8; n++){ float b = lbias[6][n*16 + colb];
    #pragma unroll
    for (int r = 0; r < 4; r++) h[n][r] += silu_f(acc[n][r] + b); }

  #pragma unroll
  for (int n = 0; n < 8; n++)
    #pragma unroll
    for (int r = 0; r < 4; r++)
      hio[(e0 + wv*16 + rgrp + r)*128 + n*16 + colb] = h[n][r];
#undef STAGE_B
#undef WRITE_A
#undef RUN_GEMM
}

extern "C" void kernel_launch(void* const* d_in, const int* in_sizes, int n_in,
                              void* d_out, int out_size, void* d_ws, size_t ws_size,
                              hipStream_t stream)
{
  const float* x    = (const float*)d_in[0];
  const float* rbf  = (const float*)d_in[1];
  const float* sbf  = (const float*)d_in[2];
  const int* idx_kj = (const int*)d_in[3];
  const int* idx_ji = (const int*)d_in[4];
  const float* rbfw = (const float*)d_in[5];
  const float* sbfw = (const float*)d_in[6];
  const float* kjw  = (const float*)d_in[7];
  const float* kjb  = (const float*)d_in[8];
  const float* jiw  = (const float*)d_in[9];
  const float* jib  = (const float*)d_in[10];
  const float* W    = (const float*)d_in[11];
  const float* bw   = (const float*)d_in[12];
  const float* bb   = (const float*)d_in[13];
  const float* lw   = (const float*)d_in[14];
  const float* lb   = (const float*)d_in[15];
  const float* aw   = (const float*)d_in[16];
  const float* ab   = (const float*)d_in[17];
  float* out = (float*)d_out;
  char* p = (char*)d_ws;

  u16* Wbf  = (u16*)p;                          // 256KB
  u16* linT = (u16*)(p + 262144);               // 288KB
  u16* xkj  = (u16*)(p + (1 << 20));            // 51.2MB
  size_t o = (1 << 20) + (size_t)E_N*256;
  u32* counts   = (u32*)(p + o);  o += (size_t)E_N*4;
  u32* cursor   = (u32*)(p + o);  o += (size_t)E_N*4;
  u32* rowstart = (u32*)(p + o);  o += (size_t)(E_N + 1)*4 + 60;
  u32* bsum     = (u32*)(p + o);  o += 1024;
  u32* boff     = (u32*)(p + o);  o += 1024;
  u32* order    = (u32*)(p + o);  o += (size_t)T_N*4;
  u16* mbuf     = (u16*)(p + o);  o += (size_t)T_N*256;
  const bool csr = (ws_size >= o);

  k_cvt_W<<<dim3(512), dim3(256), 0, stream>>>(W, Wbf);
  k_cvt_T<<<dim3(576), dim3(256), 0, stream>>>(jiw, kjw, bw, lw, aw, linT);
  if (csr){
    k_zero32<<<dim3(256), dim3(256), 0, stream>>>(counts, E_N);
    k_hist<<<dim3((T_N + 255)/256), dim3(256), 0, stream>>>(idx_ji, counts);
    k_scanA<<<dim3(NB_SCAN), dim3(1024), 0, stream>>>(counts, bsum);
    k_scanB<<<dim3(1), dim3(256), 0, stream>>>(bsum, boff);
    k_scanC<<<dim3(NB_SCAN), dim3(1024), 0, stream>>>(counts, boff, rowstart, cursor);
    k_fill<<<dim3((T_N + 255)/256), dim3(256), 0, stream>>>(idx_ji, cursor, order);
  }
  k_edge<<<dim3(E_N/64), dim3(256), 0, stream>>>(x, rbf, rbfw, linT, linT + 16384, jib, kjb, out, xkj);
  if (csr){
    k_trip<1><<<dim3((T_N + 255)/256), dim3(512), 0, stream>>>(xkj, sbf, sbfw, idx_kj, idx_ji, Wbf, out, mbuf);
    k_epi<1><<<dim3(E_N/64), dim3(256), 0, stream>>>(x, out, rowstart, order, mbuf, linT + 2*16384, bb, lb, ab);
  } else {
    k_trip<0><<<dim3((T_N + 255)/256), dim3(512), 0, stream>>>(xkj, sbf, sbfw, idx_kj, idx_ji, Wbf, out, mbuf);
    k_epi<0><<<dim3(E_N/64), dim3(256), 0, stream>>>(x, out, rowstart, order, mbuf, linT + 2*16384, bb, lb, ab);
  }
}